// Round 1
// 1880.437 us; speedup vs baseline: 1.8884x; 1.8884x over previous
//
#include <hip/hip_runtime.h>
#include <hip/hip_bf16.h>
#include <math.h>

typedef unsigned short u16;
typedef short short8 __attribute__((ext_vector_type(8)));
typedef float floatx4 __attribute__((ext_vector_type(4)));

#define NB 128    // batch
#define NT 24     // time steps
#define NE 512    // embed dim
#define NH 512    // hidden dim
#define NR 512    // factor rank
#define NTAG 400  // tags
#define NV 20000  // vocab

__device__ __forceinline__ float bfu(u16 u) {
    unsigned x = ((unsigned)u) << 16;
    return __builtin_bit_cast(float, x);
}
__device__ __forceinline__ u16 f2b(float f) {
    unsigned u = __builtin_bit_cast(unsigned, f);
    unsigned r = (u + 0x7FFFu + ((u >> 16) & 1u)) >> 16;
    return (u16)r;
}
__device__ __forceinline__ float ldin(const void* p, long i, int f32) {
    return f32 ? ((const float*)p)[i] : bfu(((const u16*)p)[i]);
}

// Detect input dtype: fp32 data's low halves produce exponent-all-ones bf16
// patterns at p~1/256; true bf16 (scale 0.02) never does.
__global__ __launch_bounds__(256) void k_detect(const void* emb, int* flag) {
    __shared__ int cnt;
    if (threadIdx.x == 0) cnt = 0;
    __syncthreads();
    const u16* p = (const u16*)emb;
    int local = 0;
    for (int i = threadIdx.x; i < 65536; i += 256) {
        if ((p[i] & 0x7F80) == 0x7F80) local++;
    }
    atomicAdd(&cnt, local);
    __syncthreads();
    if (threadIdx.x == 0) *flag = (cnt > 4) ? 1 : 0;
}

// temp2[g][b][r] = sum_t s[b][t]*Wb[g][t][r] ; temp5 likewise with Ub
__global__ __launch_bounds__(256) void k_tags(const void* __restrict__ s,
        const void* __restrict__ Wb, const void* __restrict__ Ub,
        const int* __restrict__ flagp, float* __restrict__ temp2, float* __restrict__ temp5) {
    int f32 = *flagp;
    int idx = blockIdx.x * 256 + threadIdx.x;      // over 4*NB*NR
    int r = idx & (NR - 1);
    int gb = idx >> 9;
    int b = gb & (NB - 1);
    int g = gb >> 7;
    float a2 = 0.f, a5 = 0.f;
    if (f32) {
        const float* srow = (const float*)s + b * NTAG;
        const float* wb = (const float*)Wb + (long)g * NTAG * NR + r;
        const float* ub = (const float*)Ub + (long)g * NTAG * NR + r;
        for (int t = 0; t < NTAG; t++) {
            float sv = srow[t];
            a2 += sv * wb[(long)t * NR];
            a5 += sv * ub[(long)t * NR];
        }
    } else {
        const u16* srow = (const u16*)s + b * NTAG;
        const u16* wb = (const u16*)Wb + (long)g * NTAG * NR + r;
        const u16* ub = (const u16*)Ub + (long)g * NTAG * NR + r;
        for (int t = 0; t < NTAG; t++) {
            float sv = bfu(srow[t]);
            a2 += sv * bfu(wb[(long)t * NR]);
            a5 += sv * bfu(ub[(long)t * NR]);
        }
    }
    temp2[idx] = a2;
    temp5[idx] = a5;
}

// Transpose + k-panel swizzle to bf16.
// Output layout (uint4-granular): US[((g*64 + kk)*512 + out)] holds 8 bf16,
// element j = U[g][kk*8 + j][out]  (U treated as [gate][in][out] row-major).
// With this layout, k_rec's inner loop iteration kk has lane `rr` reading
// 16B at consecutive `out` -> one contiguous 1KiB wave load (8 cache lines)
// instead of 64 scattered lines (the old [g][out][in] row-stream layout).
// z = which*4 + g: which 0 -> Ua->UaS, which 1 -> Uc->UcS.
__global__ __launch_bounds__(256) void k_tr(const void* __restrict__ Ua,
        const void* __restrict__ Uc, const int* __restrict__ flagp,
        u16* __restrict__ UaS, u16* __restrict__ UcS) {
    int f32 = *flagp;
    int z = blockIdx.z;
    int which = z >> 2, g = z & 3;
    const void* src = which ? Uc : Ua;
    u16* dst = which ? UcS : UaS;
    __shared__ u16 tile[64][65];
    int i0 = blockIdx.x * 64;   // input (in-dim) row block
    int j0 = blockIdx.y * 64;   // input (out-dim) col block
    int t = threadIdx.x;
    int il = t >> 2, js = (t & 3) * 16;
    long base = ((long)g * 512 + i0 + il) * 512 + j0 + js;
    if (f32) {
        const float* q = (const float*)src + base;
        #pragma unroll
        for (int j = 0; j < 16; j++) tile[il][js + j] = f2b(q[j]);
    } else {
        const u16* q = (const u16*)src + base;
        #pragma unroll
        for (int j = 0; j < 16; j++) tile[il][js + j] = q[j];
    }
    __syncthreads();
    // store: 512 output 16B chunks per tile (8 k-panels x 64 out cols), 2/thread
    #pragma unroll
    for (int h = 0; h < 2; h++) {
        int idx = t + h * 256;
        int kl = idx >> 6, rl = idx & 63;
        u16 outv[8] __attribute__((aligned(16)));
        #pragma unroll
        for (int j = 0; j < 8; j++) outv[j] = tile[kl * 8 + j][rl];
        long ob = ((long)(g * 64 + (i0 >> 3) + kl) * 512 + (j0 + rl)) * 8;
        *(uint4*)(dst + ob) = *(uint4*)outv;
    }
}

// MFMA GEMM, block tile 64(M) x 128(N), K=512, 256 threads (4 waves).
// MODE 0: A = emb-gather (flag dtype), B = Wa[g] (flag), epi: *temp2 -> t1m bf16
// MODE 1: A = t1m[g] bf16, B = Wc[g] (flag), epi: plain -> gx bf16
// MODE 2: A = hs bf16, B = Wout (flag), epi: +bout, swizzle (t,b)->(b,t), guard n<NV
template<int MODE>
__global__ __launch_bounds__(256) void k_mfma(const void* __restrict__ Asrc,
        const void* __restrict__ Bsrc, void* __restrict__ dst,
        const int* __restrict__ captions, const float* __restrict__ temp2,
        const void* __restrict__ bout, const int* __restrict__ flagp) {
    const int f32 = *flagp;
    const int bm = blockIdx.x * 64;
    const int bn = blockIdx.y * 128;
    const int g = blockIdx.z;
    const int NN = (MODE == 2) ? NV : NR;
    const int ldb = (MODE == 2) ? NV : NR;
    __shared__ __align__(16) u16 As[64 * 40];
    __shared__ __align__(16) u16 Bs[32 * 132];
    const int tid = threadIdx.x;
    const int sam = tid >> 2, sak = (tid & 3) * 8;      // A staging: row, k-offset
    const int sbk = tid >> 3, sbn = (tid & 7) * 16;     // B staging: k-row, n-offset
    long arow = 0;
    int azero = 0;
    if (MODE == 0) {
        int mg = bm + sam, tt = mg >> 7, bb = mg & (NB - 1);
        if (tt == 0) azero = 1;
        else arow = (long)captions[bb * NT + tt - 1] * NE;
    } else if (MODE == 1) {
        arow = ((long)g * NT * NB + bm + sam) * NR;
    } else {
        arow = (long)(bm + sam) * NH;
    }
    long bbase;
    if (MODE == 2) bbase = bn + sbn;
    else bbase = (long)g * 512 * 512 + bn + sbn;
    const int bguard = (MODE == 2) && (bn + 128 > NN);

    const int wv = tid >> 6, ln = tid & 63;
    const int q = ln >> 4, l15 = ln & 15;
    floatx4 acc[4][2];
    #pragma unroll
    for (int i = 0; i < 4; i++)
        #pragma unroll
        for (int j = 0; j < 2; j++)
            #pragma unroll
            for (int r = 0; r < 4; r++) acc[i][j][r] = 0.f;

    for (int k0 = 0; k0 < 512; k0 += 32) {
        // ---- stage A (8 elems/thread) ----
        u16 ta[8] __attribute__((aligned(16)));
        if (MODE == 0) {
            if (azero) {
                #pragma unroll
                for (int j = 0; j < 8; j++) ta[j] = 0;
            } else if (f32) {
                const float* qa = (const float*)Asrc + arow + k0 + sak;
                #pragma unroll
                for (int j = 0; j < 8; j++) ta[j] = f2b(qa[j]);
            } else {
                *(uint4*)ta = *(const uint4*)((const u16*)Asrc + arow + k0 + sak);
            }
        } else {
            *(uint4*)ta = *(const uint4*)((const u16*)Asrc + arow + k0 + sak);
        }
        *(uint4*)&As[sam * 40 + sak] = *(uint4*)ta;
        // ---- stage B (16 elems/thread, natural [k][n]) ----
        u16 tb[16] __attribute__((aligned(16)));
        long be = bbase + (long)(k0 + sbk) * ldb;
        if (!bguard) {
            if (f32) {
                const float* qb = (const float*)Bsrc + be;
                #pragma unroll
                for (int j = 0; j < 16; j++) tb[j] = f2b(qb[j]);
            } else {
                *(uint4*)tb = *(const uint4*)((const u16*)Bsrc + be);
                *(uint4*)(tb + 8) = *(const uint4*)((const u16*)Bsrc + be + 8);
            }
        } else {
            #pragma unroll
            for (int j = 0; j < 16; j++) {
                int n = bn + sbn + j;
                tb[j] = (n < NN) ? (f32 ? f2b(((const float*)Bsrc)[be + j])
                                        : ((const u16*)Bsrc)[be + j]) : (u16)0;
            }
        }
        *(uint2*)&Bs[sbk * 132 + sbn]      = *(uint2*)tb;
        *(uint2*)&Bs[sbk * 132 + sbn + 4]  = *(uint2*)(tb + 4);
        *(uint2*)&Bs[sbk * 132 + sbn + 8]  = *(uint2*)(tb + 8);
        *(uint2*)&Bs[sbk * 132 + sbn + 12] = *(uint2*)(tb + 12);
        __syncthreads();
        // ---- fragments + MFMA ----
        short8 af[4];
        #pragma unroll
        for (int mi = 0; mi < 4; mi++)
            af[mi] = *(const short8*)&As[(mi * 16 + l15) * 40 + q * 8];
        #pragma unroll
        for (int ni = 0; ni < 2; ni++) {
            union { u16 u[8]; short8 v; } bu;
            int n = wv * 32 + ni * 16 + l15;
            #pragma unroll
            for (int j = 0; j < 8; j++) bu.u[j] = Bs[(q * 8 + j) * 132 + n];
            #pragma unroll
            for (int mi = 0; mi < 4; mi++)
                acc[mi][ni] = __builtin_amdgcn_mfma_f32_16x16x32_bf16(af[mi], bu.v, acc[mi][ni], 0, 0, 0);
        }
        __syncthreads();
    }
    // ---- epilogue ----
    #pragma unroll
    for (int mi = 0; mi < 4; mi++) {
        #pragma unroll
        for (int ni = 0; ni < 2; ni++) {
            int n = bn + wv * 32 + ni * 16 + l15;
            #pragma unroll
            for (int r = 0; r < 4; r++) {
                int m = bm + mi * 16 + q * 4 + r;
                float v = acc[mi][ni][r];
                if (MODE == 0) {
                    int bb = m & (NB - 1);
                    v *= temp2[((long)g * NB + bb) * NR + n];
                    ((u16*)dst)[((long)g * NT * NB + m) * NR + n] = f2b(v);
                } else if (MODE == 1) {
                    ((u16*)dst)[((long)g * NT * NB + m) * NR + n] = f2b(v);
                } else {
                    if (n < NV) {
                        int tt = m >> 7, bb = m & (NB - 1);
                        float o = v + ldin(bout, n, f32);
                        long oi = ((long)bb * NT + tt) * NV + n;
                        if (f32) ((float*)dst)[oi] = o;
                        else ((u16*)dst)[oi] = f2b(o);
                    }
                }
            }
        }
    }
}

// Whole recurrence in one kernel: block = one batch row b, 1024 threads, 24 steps.
// Thread handles gates (g, g+2) at index rr for both phases.
// Weights come in k-panel layout (see k_tr): at iteration kk, the wave's 64
// lanes read one contiguous 1KiB block -> coalesced (was 64 lines/load).
__global__ __launch_bounds__(1024) void k_rec(const u16* __restrict__ UaS,
        const u16* __restrict__ UcS, const float* __restrict__ temp5,
        const u16* __restrict__ gx, const void* __restrict__ bias,
        const void* __restrict__ h0, const void* __restrict__ c0,
        const int* __restrict__ flagp, u16* __restrict__ hs) {
    const int f32 = *flagp;
    const int b = blockIdx.x;
    __shared__ __align__(16) u16 hb[NH];
    __shared__ __align__(16) u16 t6[4 * NR];
    __shared__ float cl[NH];
    __shared__ float pre[4 * NH];
    const int tid = threadIdx.x;
    if (tid < NH) {
        hb[tid] = f2b(ldin(h0, (long)b * NH + tid, f32));
        cl[tid] = ldin(c0, (long)b * NH + tid, f32);
    }
    const int g = tid >> 9;       // 0 or 1 (second output is gate g+2)
    const int rr = tid & 511;
    // k-panel layout: uint4 index ((g*64 + kk)*512 + rr), stride 512 per kk
    const uint4* rA0 = (const uint4*)UaS + (long)g * 64 * 512 + rr;
    const uint4* rA1 = (const uint4*)UaS + (long)(g + 2) * 64 * 512 + rr;
    const uint4* rB0 = (const uint4*)UcS + (long)g * 64 * 512 + rr;
    const uint4* rB1 = (const uint4*)UcS + (long)(g + 2) * 64 * 512 + rr;
    const float t5a = temp5[((long)g * NB + b) * NR + rr];
    const float t5b = temp5[((long)(g + 2) * NB + b) * NR + rr];
    const float bia = ldin(bias, g * NH + rr, f32);
    const float bib = ldin(bias, (g + 2) * NH + rr, f32);
    __syncthreads();
    for (int t = 0; t < NT; t++) {
        // phase A: temp6[g][rr] = (h . Ua[:,rr]) * temp5
        float a0 = 0.f, a1 = 0.f;
        const uint4* hv4 = (const uint4*)hb;
        #pragma unroll 4
        for (int kk = 0; kk < 64; kk++) {
            uint4 h4 = hv4[kk];                 // LDS broadcast (uniform addr)
            uint4 w0 = rA0[kk * 512], w1 = rA1[kk * 512];
            const unsigned* hp = (const unsigned*)&h4;
            const unsigned* p0 = (const unsigned*)&w0;
            const unsigned* p1 = (const unsigned*)&w1;
            #pragma unroll
            for (int i = 0; i < 4; i++) {
                float hl = __builtin_bit_cast(float, hp[i] << 16);
                float hh = __builtin_bit_cast(float, hp[i] & 0xFFFF0000u);
                a0 = fmaf(__builtin_bit_cast(float, p0[i] << 16), hl, a0);
                a0 = fmaf(__builtin_bit_cast(float, p0[i] & 0xFFFF0000u), hh, a0);
                a1 = fmaf(__builtin_bit_cast(float, p1[i] << 16), hl, a1);
                a1 = fmaf(__builtin_bit_cast(float, p1[i] & 0xFFFF0000u), hh, a1);
            }
        }
        t6[g * NR + rr] = f2b(a0 * t5a);
        t6[(g + 2) * NR + rr] = f2b(a1 * t5b);
        __syncthreads();
        // phase B: pre[g][rr] = (temp6[g] . Uc[:,rr]) + gx + bias
        float s0 = 0.f, s1 = 0.f;
        const uint4* tv0 = (const uint4*)(t6 + g * NR);
        const uint4* tv1 = (const uint4*)(t6 + (g + 2) * NR);
        #pragma unroll 4
        for (int kk = 0; kk < 64; kk++) {
            uint4 x0 = tv0[kk], x1 = tv1[kk];   // LDS broadcast
            uint4 w0 = rB0[kk * 512], w1 = rB1[kk * 512];
            const unsigned* a0p = (const unsigned*)&x0;
            const unsigned* a1p = (const unsigned*)&x1;
            const unsigned* p0 = (const unsigned*)&w0;
            const unsigned* p1 = (const unsigned*)&w1;
            #pragma unroll
            for (int i = 0; i < 4; i++) {
                s0 = fmaf(__builtin_bit_cast(float, p0[i] << 16),
                          __builtin_bit_cast(float, a0p[i] << 16), s0);
                s0 = fmaf(__builtin_bit_cast(float, p0[i] & 0xFFFF0000u),
                          __builtin_bit_cast(float, a0p[i] & 0xFFFF0000u), s0);
                s1 = fmaf(__builtin_bit_cast(float, p1[i] << 16),
                          __builtin_bit_cast(float, a1p[i] << 16), s1);
                s1 = fmaf(__builtin_bit_cast(float, p1[i] & 0xFFFF0000u),
                          __builtin_bit_cast(float, a1p[i] & 0xFFFF0000u), s1);
            }
        }
        long gi0 = (((long)g * NT + t) * NB + b) * NH + rr;
        long gi1 = (((long)(g + 2) * NT + t) * NB + b) * NH + rr;
        pre[g * NH + rr] = s0 + bfu(gx[gi0]) + bia;
        pre[(g + 2) * NH + rr] = s1 + bfu(gx[gi1]) + bib;
        __syncthreads();
        // pointwise LSTM
        if (tid < NH) {
            float ig = 1.f / (1.f + expf(-pre[tid]));
            float fg = 1.f / (1.f + expf(-pre[NH + tid]));
            float og = 1.f / (1.f + expf(-pre[2 * NH + tid]));
            float ct = tanhf(pre[3 * NH + tid]);
            float cn = fg * cl[tid] + ig * ct;
            float hn = og * tanhf(cn);
            cl[tid] = cn;
            u16 hv = f2b(hn);
            hb[tid] = hv;
            hs[((long)t * NB + b) * NH + tid] = hv;
        }
        __syncthreads();
    }
}

extern "C" void kernel_launch(void* const* d_in, const int* in_sizes, int n_in,
                              void* d_out, int out_size, void* d_ws, size_t ws_size,
                              hipStream_t stream) {
    const int* captions = (const int*)d_in[0];
    const void* s    = d_in[1];
    const void* h0   = d_in[2];
    const void* c0   = d_in[3];
    const void* Wa   = d_in[4];
    const void* Wb   = d_in[5];
    const void* Wc   = d_in[6];
    const void* Ua   = d_in[7];
    const void* Ub   = d_in[8];
    const void* Uc   = d_in[9];
    const void* bias = d_in[10];
    const void* emb  = d_in[11];
    const void* Wout = d_in[12];
    const void* bout = d_in[13];

    // workspace (~31.5 MB)
    char* w = (char*)d_ws;
    int*   flag  = (int*)w;                                  // 256 B
    float* temp2 = (float*)(w + 256);                        // 1 MB
    float* temp5 = temp2 + 4 * NB * NR;                      // 1 MB
    u16*   UaS   = (u16*)(temp5 + 4 * NB * NR);              // 2 MB bf16 (k-panel)
    u16*   UcS   = UaS + 4 * 512 * 512;                      // 2 MB bf16 (k-panel)
    u16*   t1m   = UcS + 4 * 512 * 512;                      // 12.6 MB bf16
    u16*   gx    = t1m + (long)4 * NT * NB * NR;             // 12.6 MB bf16
    u16*   hs    = t1m;  // alias: t1m dead after k_mfma<1>

    dim3 blk(256);
    k_detect<<<1, blk, 0, stream>>>(emb, flag);
    k_tags<<<(4 * NB * NR) / 256, blk, 0, stream>>>(s, Wb, Ub, flag, temp2, temp5);
    k_tr<<<dim3(8, 8, 8), blk, 0, stream>>>(Ua, Uc, flag, UaS, UcS);

    // hoisted input path (MFMA)
    k_mfma<0><<<dim3(48, 4, 4), blk, 0, stream>>>(emb, Wa, t1m, captions, temp2, nullptr, flag);
    k_mfma<1><<<dim3(48, 4, 4), blk, 0, stream>>>(t1m, Wc, gx, nullptr, nullptr, nullptr, flag);

    // fused recurrence: one launch, one block per batch row
    k_rec<<<128, 1024, 0, stream>>>(UaS, UcS, temp5, gx, bias, h0, c0, flag, hs);

    // output projection (MFMA), grid.x = M-tiles so consecutive blocks share W strip in L2
    k_mfma<2><<<dim3(48, 157, 1), blk, 0, stream>>>(hs, Wout, d_out, nullptr, nullptr, bout, flag);
}

// Round 2
// 1428.152 us; speedup vs baseline: 2.4865x; 1.3167x over previous
//
#include <hip/hip_runtime.h>
#include <hip/hip_bf16.h>
#include <math.h>

typedef unsigned short u16;
typedef short short8 __attribute__((ext_vector_type(8)));
typedef float floatx4 __attribute__((ext_vector_type(4)));

#define NB 128    // batch
#define NT 24     // time steps
#define NE 512    // embed dim
#define NH 512    // hidden dim
#define NR 512    // factor rank
#define NTAG 400  // tags
#define NV 20000  // vocab

__device__ __forceinline__ float bfu(u16 u) {
    unsigned x = ((unsigned)u) << 16;
    return __builtin_bit_cast(float, x);
}
__device__ __forceinline__ u16 f2b(float f) {
    unsigned u = __builtin_bit_cast(unsigned, f);
    unsigned r = (u + 0x7FFFu + ((u >> 16) & 1u)) >> 16;
    return (u16)r;
}
__device__ __forceinline__ float ldin(const void* p, long i, int f32) {
    return f32 ? ((const float*)p)[i] : bfu(((const u16*)p)[i]);
}

// Detect input dtype: fp32 data's low halves produce exponent-all-ones bf16
// patterns at p~1/256; true bf16 (scale 0.02) never does.
__global__ __launch_bounds__(256) void k_detect(const void* emb, int* flag) {
    __shared__ int cnt;
    if (threadIdx.x == 0) cnt = 0;
    __syncthreads();
    const u16* p = (const u16*)emb;
    int local = 0;
    for (int i = threadIdx.x; i < 65536; i += 256) {
        if ((p[i] & 0x7F80) == 0x7F80) local++;
    }
    atomicAdd(&cnt, local);
    __syncthreads();
    if (threadIdx.x == 0) *flag = (cnt > 4) ? 1 : 0;
}

// temp2[g][b][r] = sum_t s[b][t]*Wb[g][t][r] ; temp5 likewise with Ub
// Also zeroes the k_rec sync flags (stream-ordered before k_rec).
__global__ __launch_bounds__(256) void k_tags(const void* __restrict__ s,
        const void* __restrict__ Wb, const void* __restrict__ Ub,
        const int* __restrict__ flagp, float* __restrict__ temp2, float* __restrict__ temp5,
        int* __restrict__ flags) {
    if (blockIdx.x == 0 && threadIdx.x < 256) flags[threadIdx.x] = 0;
    int f32 = *flagp;
    int idx = blockIdx.x * 256 + threadIdx.x;      // over 4*NB*NR
    int r = idx & (NR - 1);
    int gb = idx >> 9;
    int b = gb & (NB - 1);
    int g = gb >> 7;
    float a2 = 0.f, a5 = 0.f;
    if (f32) {
        const float* srow = (const float*)s + b * NTAG;
        const float* wb = (const float*)Wb + (long)g * NTAG * NR + r;
        const float* ub = (const float*)Ub + (long)g * NTAG * NR + r;
        for (int t = 0; t < NTAG; t++) {
            float sv = srow[t];
            a2 += sv * wb[(long)t * NR];
            a5 += sv * ub[(long)t * NR];
        }
    } else {
        const u16* srow = (const u16*)s + b * NTAG;
        const u16* wb = (const u16*)Wb + (long)g * NTAG * NR + r;
        const u16* ub = (const u16*)Ub + (long)g * NTAG * NR + r;
        for (int t = 0; t < NTAG; t++) {
            float sv = bfu(srow[t]);
            a2 += sv * bfu(wb[(long)t * NR]);
            a5 += sv * bfu(ub[(long)t * NR]);
        }
    }
    temp2[idx] = a2;
    temp5[idx] = a5;
}

// Transpose + k-panel swizzle to bf16.
// Output layout (uint4-granular): US[((g*64 + kk)*512 + out)] holds 8 bf16,
// element j = U[g][kk*8 + j][out]  (U treated as [gate][in][out] row-major).
// z = which*4 + g: which 0 -> Ua->UaS, which 1 -> Uc->UcS.
__global__ __launch_bounds__(256) void k_tr(const void* __restrict__ Ua,
        const void* __restrict__ Uc, const int* __restrict__ flagp,
        u16* __restrict__ UaS, u16* __restrict__ UcS) {
    int f32 = *flagp;
    int z = blockIdx.z;
    int which = z >> 2, g = z & 3;
    const void* src = which ? Uc : Ua;
    u16* dst = which ? UcS : UaS;
    __shared__ u16 tile[64][65];
    int i0 = blockIdx.x * 64;   // input (in-dim) row block
    int j0 = blockIdx.y * 64;   // input (out-dim) col block
    int t = threadIdx.x;
    int il = t >> 2, js = (t & 3) * 16;
    long base = ((long)g * 512 + i0 + il) * 512 + j0 + js;
    if (f32) {
        const float* q = (const float*)src + base;
        #pragma unroll
        for (int j = 0; j < 16; j++) tile[il][js + j] = f2b(q[j]);
    } else {
        const u16* q = (const u16*)src + base;
        #pragma unroll
        for (int j = 0; j < 16; j++) tile[il][js + j] = q[j];
    }
    __syncthreads();
    // store: 512 output 16B chunks per tile (8 k-panels x 64 out cols), 2/thread
    #pragma unroll
    for (int h = 0; h < 2; h++) {
        int idx = t + h * 256;
        int kl = idx >> 6, rl = idx & 63;
        u16 outv[8] __attribute__((aligned(16)));
        #pragma unroll
        for (int j = 0; j < 8; j++) outv[j] = tile[kl * 8 + j][rl];
        long ob = ((long)(g * 64 + (i0 >> 3) + kl) * 512 + (j0 + rl)) * 8;
        *(uint4*)(dst + ob) = *(uint4*)outv;
    }
}

// MFMA GEMM, block tile 64(M) x 128(N), K=512, 256 threads (4 waves).
// MODE 0: A = emb-gather (flag dtype), B = Wa[g] (flag), epi: *temp2 -> t1m bf16
// MODE 1: A = t1m[g] bf16, B = Wc[g] (flag), epi: plain -> gx bf16
// MODE 2: A = hs bf16, B = Wout (flag), epi: +bout, swizzle (t,b)->(b,t), guard n<NV
template<int MODE>
__global__ __launch_bounds__(256) void k_mfma(const void* __restrict__ Asrc,
        const void* __restrict__ Bsrc, void* __restrict__ dst,
        const int* __restrict__ captions, const float* __restrict__ temp2,
        const void* __restrict__ bout, const int* __restrict__ flagp) {
    const int f32 = *flagp;
    const int bm = blockIdx.x * 64;
    const int bn = blockIdx.y * 128;
    const int g = blockIdx.z;
    const int NN = (MODE == 2) ? NV : NR;
    const int ldb = (MODE == 2) ? NV : NR;
    __shared__ __align__(16) u16 As[64 * 40];
    __shared__ __align__(16) u16 Bs[32 * 132];
    const int tid = threadIdx.x;
    const int sam = tid >> 2, sak = (tid & 3) * 8;      // A staging: row, k-offset
    const int sbk = tid >> 3, sbn = (tid & 7) * 16;     // B staging: k-row, n-offset
    long arow = 0;
    int azero = 0;
    if (MODE == 0) {
        int mg = bm + sam, tt = mg >> 7, bb = mg & (NB - 1);
        if (tt == 0) azero = 1;
        else arow = (long)captions[bb * NT + tt - 1] * NE;
    } else if (MODE == 1) {
        arow = ((long)g * NT * NB + bm + sam) * NR;
    } else {
        arow = (long)(bm + sam) * NH;
    }
    long bbase;
    if (MODE == 2) bbase = bn + sbn;
    else bbase = (long)g * 512 * 512 + bn + sbn;
    const int bguard = (MODE == 2) && (bn + 128 > NN);

    const int wv = tid >> 6, ln = tid & 63;
    const int q = ln >> 4, l15 = ln & 15;
    floatx4 acc[4][2];
    #pragma unroll
    for (int i = 0; i < 4; i++)
        #pragma unroll
        for (int j = 0; j < 2; j++)
            #pragma unroll
            for (int r = 0; r < 4; r++) acc[i][j][r] = 0.f;

    for (int k0 = 0; k0 < 512; k0 += 32) {
        // ---- stage A (8 elems/thread) ----
        u16 ta[8] __attribute__((aligned(16)));
        if (MODE == 0) {
            if (azero) {
                #pragma unroll
                for (int j = 0; j < 8; j++) ta[j] = 0;
            } else if (f32) {
                const float* qa = (const float*)Asrc + arow + k0 + sak;
                #pragma unroll
                for (int j = 0; j < 8; j++) ta[j] = f2b(qa[j]);
            } else {
                *(uint4*)ta = *(const uint4*)((const u16*)Asrc + arow + k0 + sak);
            }
        } else {
            *(uint4*)ta = *(const uint4*)((const u16*)Asrc + arow + k0 + sak);
        }
        *(uint4*)&As[sam * 40 + sak] = *(uint4*)ta;
        // ---- stage B (16 elems/thread, natural [k][n]) ----
        u16 tb[16] __attribute__((aligned(16)));
        long be = bbase + (long)(k0 + sbk) * ldb;
        if (!bguard) {
            if (f32) {
                const float* qb = (const float*)Bsrc + be;
                #pragma unroll
                for (int j = 0; j < 16; j++) tb[j] = f2b(qb[j]);
            } else {
                *(uint4*)tb = *(const uint4*)((const u16*)Bsrc + be);
                *(uint4*)(tb + 8) = *(const uint4*)((const u16*)Bsrc + be + 8);
            }
        } else {
            #pragma unroll
            for (int j = 0; j < 16; j++) {
                int n = bn + sbn + j;
                tb[j] = (n < NN) ? (f32 ? f2b(((const float*)Bsrc)[be + j])
                                        : ((const u16*)Bsrc)[be + j]) : (u16)0;
            }
        }
        *(uint2*)&Bs[sbk * 132 + sbn]      = *(uint2*)tb;
        *(uint2*)&Bs[sbk * 132 + sbn + 4]  = *(uint2*)(tb + 4);
        *(uint2*)&Bs[sbk * 132 + sbn + 8]  = *(uint2*)(tb + 8);
        *(uint2*)&Bs[sbk * 132 + sbn + 12] = *(uint2*)(tb + 12);
        __syncthreads();
        // ---- fragments + MFMA ----
        short8 af[4];
        #pragma unroll
        for (int mi = 0; mi < 4; mi++)
            af[mi] = *(const short8*)&As[(mi * 16 + l15) * 40 + q * 8];
        #pragma unroll
        for (int ni = 0; ni < 2; ni++) {
            union { u16 u[8]; short8 v; } bu;
            int n = wv * 32 + ni * 16 + l15;
            #pragma unroll
            for (int j = 0; j < 8; j++) bu.u[j] = Bs[(q * 8 + j) * 132 + n];
            #pragma unroll
            for (int mi = 0; mi < 4; mi++)
                acc[mi][ni] = __builtin_amdgcn_mfma_f32_16x16x32_bf16(af[mi], bu.v, acc[mi][ni], 0, 0, 0);
        }
        __syncthreads();
    }
    // ---- epilogue ----
    #pragma unroll
    for (int mi = 0; mi < 4; mi++) {
        #pragma unroll
        for (int ni = 0; ni < 2; ni++) {
            int n = bn + wv * 32 + ni * 16 + l15;
            #pragma unroll
            for (int r = 0; r < 4; r++) {
                int m = bm + mi * 16 + q * 4 + r;
                float v = acc[mi][ni][r];
                if (MODE == 0) {
                    int bb = m & (NB - 1);
                    v *= temp2[((long)g * NB + bb) * NR + n];
                    ((u16*)dst)[((long)g * NT * NB + m) * NR + n] = f2b(v);
                } else if (MODE == 1) {
                    ((u16*)dst)[((long)g * NT * NB + m) * NR + n] = f2b(v);
                } else {
                    if (n < NV) {
                        int tt = m >> 7, bb = m & (NB - 1);
                        float o = v + ldin(bout, n, f32);
                        long oi = ((long)bb * NT + tt) * NV + n;
                        if (f32) ((float*)dst)[oi] = o;
                        else ((u16*)dst)[oi] = f2b(o);
                    }
                }
            }
        }
    }
}

// Dual-column dot: a0 = x0 . col(w0p), a1 = x1 . col(w1p), K=512.
// Weights bf16 in k-panel layout (uint4 stride 512 per 8-elem chunk);
// x arrays are f32 in LDS (broadcast reads). 2-deep chunk prefetch.
template<bool SHARED>
__device__ __forceinline__ void dot2(const uint4* __restrict__ w0p,
        const uint4* __restrict__ w1p, const float* __restrict__ x0,
        const float* __restrict__ x1, float& o0, float& o1) {
    float a0 = 0.f, a1 = 0.f;
    uint4 c0[4], c1[4], n0[4], n1[4];
    #pragma unroll
    for (int j = 0; j < 4; j++) { c0[j] = w0p[j * 512]; c1[j] = w1p[j * 512]; }
    #pragma unroll 2
    for (int cc = 0; cc < 16; cc++) {
        if (cc < 15) {
            #pragma unroll
            for (int j = 0; j < 4; j++) {
                n0[j] = w0p[(cc * 4 + 4 + j) * 512];
                n1[j] = w1p[(cc * 4 + 4 + j) * 512];
            }
        }
        #pragma unroll
        for (int j = 0; j < 4; j++) {
            const int kb = (cc * 4 + j) * 8;
            const unsigned* p0 = (const unsigned*)&c0[j];
            const unsigned* p1 = (const unsigned*)&c1[j];
            #pragma unroll
            for (int i = 0; i < 4; i++) {
                float xl0 = x0[kb + 2 * i], xh0 = x0[kb + 2 * i + 1];
                a0 = fmaf(__builtin_bit_cast(float, p0[i] << 16), xl0, a0);
                a0 = fmaf(__builtin_bit_cast(float, p0[i] & 0xFFFF0000u), xh0, a0);
                if (SHARED) {
                    a1 = fmaf(__builtin_bit_cast(float, p1[i] << 16), xl0, a1);
                    a1 = fmaf(__builtin_bit_cast(float, p1[i] & 0xFFFF0000u), xh0, a1);
                } else {
                    float xl1 = x1[kb + 2 * i], xh1 = x1[kb + 2 * i + 1];
                    a1 = fmaf(__builtin_bit_cast(float, p1[i] << 16), xl1, a1);
                    a1 = fmaf(__builtin_bit_cast(float, p1[i] & 0xFFFF0000u), xh1, a1);
                }
            }
        }
        #pragma unroll
        for (int j = 0; j < 4; j++) { c0[j] = n0[j]; c1[j] = n1[j]; }
    }
    o0 = a0; o1 = a1;
}

// Recurrence split across 2 blocks per batch row: block (b,p) owns gates
// (p, p+2). Per step the blocks exchange their 2 pre-activation vectors via
// agent-scope atomics (parity double-buffered) + release/acquire flag
// handshake, then both redundantly compute the pointwise LSTM update.
// All 256 blocks are co-resident (2048 waves << 8192) -> no deadlock.
// h and t6 kept f32 in LDS (no unpack on the x side, closer to reference).
__global__ __launch_bounds__(512, 2) void k_rec(const u16* __restrict__ UaS,
        const u16* __restrict__ UcS, const float* __restrict__ temp5,
        const u16* __restrict__ gx, const void* __restrict__ bias,
        const void* __restrict__ h0, const void* __restrict__ c0,
        const int* __restrict__ flagp, u16* __restrict__ hs,
        float* __restrict__ preX, int* __restrict__ flags) {
    const int f32 = *flagp;
    const int b = blockIdx.x;
    const int p = blockIdx.y;           // 0: gates (i,o)=(0,2); 1: (f,c~)=(1,3)
    __shared__ __align__(16) float hf[NH];
    __shared__ __align__(16) float t6f[2 * NR];
    const int tid = threadIdx.x;        // rr / h index
    hf[tid] = ldin(h0, (long)b * NH + tid, f32);
    float cstate = ldin(c0, (long)b * NH + tid, f32);
    const int gA = p, gB = p + 2;
    const uint4* rA0 = (const uint4*)UaS + (long)gA * 64 * 512 + tid;
    const uint4* rA1 = (const uint4*)UaS + (long)gB * 64 * 512 + tid;
    const uint4* rB0 = (const uint4*)UcS + (long)gA * 64 * 512 + tid;
    const uint4* rB1 = (const uint4*)UcS + (long)gB * 64 * 512 + tid;
    const float t5a = temp5[((long)gA * NB + b) * NR + tid];
    const float t5b = temp5[((long)gB * NB + b) * NR + tid];
    const float bia = ldin(bias, gA * NH + tid, f32);
    const float bib = ldin(bias, gB * NH + tid, f32);
    int* myFlag = &flags[b * 2 + p];
    int* otFlag = &flags[b * 2 + (1 - p)];
    __syncthreads();
    for (int t = 0; t < NT; t++) {
        // phase A: t6[g][rr] = (h . Ua col rr) * temp5
        float a0, a1;
        dot2<true>(rA0, rA1, hf, hf, a0, a1);
        t6f[tid] = a0 * t5a;
        t6f[NR + tid] = a1 * t5b;
        __syncthreads();
        // phase B: pre[g][rr] = (t6[g] . Uc col rr) + gx + bias
        float gxa = bfu(gx[(((long)gA * NT + t) * NB + b) * NH + tid]);
        float gxb = bfu(gx[(((long)gB * NT + t) * NB + b) * NH + tid]);
        float s0, s1;
        dot2<false>(rB0, rB1, t6f, t6f + NR, s0, s1);
        float pre0 = s0 + gxa + bia;
        float pre1 = s1 + gxb + bib;
        // ---- exchange with partner block (parity double-buffer) ----
        float* myPre = preX + ((((long)b * 2 + p) * 2 + (t & 1)) * 2) * NH;
        const float* otPre = preX + ((((long)b * 2 + (1 - p)) * 2 + (t & 1)) * 2) * NH;
        __hip_atomic_store(&myPre[tid], pre0, __ATOMIC_RELAXED, __HIP_MEMORY_SCOPE_AGENT);
        __hip_atomic_store(&myPre[NH + tid], pre1, __ATOMIC_RELAXED, __HIP_MEMORY_SCOPE_AGENT);
        __syncthreads();   // drains all threads' stores (vmcnt0 before barrier)
        if (tid == 0) {
            __hip_atomic_store(myFlag, t + 1, __ATOMIC_RELEASE, __HIP_MEMORY_SCOPE_AGENT);
            while (__hip_atomic_load(otFlag, __ATOMIC_RELAXED, __HIP_MEMORY_SCOPE_AGENT) < t + 1)
                __builtin_amdgcn_s_sleep(2);
            __builtin_amdgcn_fence(__ATOMIC_ACQUIRE, "agent");
        }
        __syncthreads();
        float q0 = __hip_atomic_load(&otPre[tid], __ATOMIC_RELAXED, __HIP_MEMORY_SCOPE_AGENT);
        float q1 = __hip_atomic_load(&otPre[NH + tid], __ATOMIC_RELAXED, __HIP_MEMORY_SCOPE_AGENT);
        // gate order along axis 0: (i, f, o, c~)
        float pi, pf, po, pc;
        if (p == 0) { pi = pre0; po = pre1; pf = q0; pc = q1; }
        else        { pf = pre0; pc = pre1; pi = q0; po = q1; }
        float ig = 1.f / (1.f + expf(-pi));
        float fg = 1.f / (1.f + expf(-pf));
        float og = 1.f / (1.f + expf(-po));
        float ct = tanhf(pc);
        float cn = fg * cstate + ig * ct;
        float hn = og * tanhf(cn);
        cstate = cn;
        hf[tid] = hn;                    // safe: all phase-A reads done pre-barrier
        if (p == 0) hs[((long)t * NB + b) * NH + tid] = f2b(hn);
        __syncthreads();
    }
}

extern "C" void kernel_launch(void* const* d_in, const int* in_sizes, int n_in,
                              void* d_out, int out_size, void* d_ws, size_t ws_size,
                              hipStream_t stream) {
    const int* captions = (const int*)d_in[0];
    const void* s    = d_in[1];
    const void* h0   = d_in[2];
    const void* c0   = d_in[3];
    const void* Wa   = d_in[4];
    const void* Wb   = d_in[5];
    const void* Wc   = d_in[6];
    const void* Ua   = d_in[7];
    const void* Ub   = d_in[8];
    const void* Uc   = d_in[9];
    const void* bias = d_in[10];
    const void* emb  = d_in[11];
    const void* Wout = d_in[12];
    const void* bout = d_in[13];

    // workspace (~35.3 MB)
    char* w = (char*)d_ws;
    int*   flag  = (int*)w;                                  // 256 B
    int*   flags = (int*)(w + 256);                          // 1 KB (256 ints)
    float* temp2 = (float*)(w + 2048);                       // 1 MB
    float* temp5 = temp2 + 4 * NB * NR;                      // 1 MB
    u16*   UaS   = (u16*)(temp5 + 4 * NB * NR);              // 2 MB bf16 (k-panel)
    u16*   UcS   = UaS + 4 * 512 * 512;                      // 2 MB bf16 (k-panel)
    u16*   t1m   = UcS + 4 * 512 * 512;                      // 12.6 MB bf16
    u16*   gx    = t1m + (long)4 * NT * NB * NR;             // 12.6 MB bf16
    float* preX  = (float*)(gx + (long)4 * NT * NB * NR);    // 4 MB (parity dbuf)
    u16*   hs    = t1m;  // alias: t1m dead after k_mfma<1>

    dim3 blk(256);
    k_detect<<<1, blk, 0, stream>>>(emb, flag);
    k_tags<<<(4 * NB * NR) / 256, blk, 0, stream>>>(s, Wb, Ub, flag, temp2, temp5, flags);
    k_tr<<<dim3(8, 8, 8), blk, 0, stream>>>(Ua, Uc, flag, UaS, UcS);

    // hoisted input path (MFMA)
    k_mfma<0><<<dim3(48, 4, 4), blk, 0, stream>>>(emb, Wa, t1m, captions, temp2, nullptr, flag);
    k_mfma<1><<<dim3(48, 4, 4), blk, 0, stream>>>(t1m, Wc, gx, nullptr, nullptr, nullptr, flag);

    // fused recurrence: 2 blocks per batch row (gate-pair split), flag handshake.
    // grid (128,2): partners are 128 apart in linear id == same XCD (id%8 equal).
    k_rec<<<dim3(128, 2), 512, 0, stream>>>(UaS, UcS, temp5, gx, bias, h0, c0, flag, hs, preX, flags);

    // output projection (MFMA), grid.x = M-tiles so consecutive blocks share W strip in L2
    k_mfma<2><<<dim3(48, 157, 1), blk, 0, stream>>>(hs, Wout, d_out, nullptr, nullptr, bout, flag);
}